// Round 10
// baseline (1168.499 us; speedup 1.0000x reference)
//
#include <hip/hip_runtime.h>
#include <stdint.h>

typedef __attribute__((ext_vector_type(4))) int i32x4;
typedef __attribute__((ext_vector_type(16))) int i32x16;

typedef const __attribute__((address_space(1))) void gvoid_t;
typedef __attribute__((address_space(3))) void lvoid_t;

#define GLD16(g, l) __builtin_amdgcn_global_load_lds((gvoid_t*)(g), (lvoid_t*)(l), 16, 0, 0)
#define FENCE() asm volatile("" ::: "memory")
#define BARRIER() do { FENCE(); __builtin_amdgcn_s_barrier(); FENCE(); } while (0)
#define SCHEDB() __builtin_amdgcn_sched_barrier(0)
#define GATE(n) asm volatile("s_waitcnt vmcnt(" #n ")\n\ts_barrier" ::: "memory")

__device__ inline int q1mul(float x, float r) {
    return (int)fminf(fmaxf(rintf(x * r), -128.f), 127.f);
}
__device__ inline int q1div(float x, float s) {
    return (int)fminf(fmaxf(rintf(x / s), -128.f), 127.f);
}
__device__ inline int pack4(float4 v, float r) {
    return (q1mul(v.x, r) & 255) | ((q1mul(v.y, r) & 255) << 8) |
           ((q1mul(v.z, r) & 255) << 16) | ((q1mul(v.w, r) & 255) << 24);
}

// ---------------- global absmax (4 independent chains) ----------------
__global__ void k_absmax(const float* __restrict__ x, size_t n4, unsigned int* __restrict__ out) {
    size_t S = (size_t)gridDim.x * blockDim.x;
    size_t i = (size_t)blockIdx.x * blockDim.x + threadIdx.x;
    const float4* x4 = (const float4*)x;
    float m0 = 0.f, m1 = 0.f, m2 = 0.f, m3 = 0.f;
    for (; i + 3 * S < n4; i += 4 * S) {
        float4 v0 = x4[i], v1 = x4[i + S], v2 = x4[i + 2 * S], v3 = x4[i + 3 * S];
        m0 = fmaxf(m0, fmaxf(fmaxf(fabsf(v0.x), fabsf(v0.y)), fmaxf(fabsf(v0.z), fabsf(v0.w))));
        m1 = fmaxf(m1, fmaxf(fmaxf(fabsf(v1.x), fabsf(v1.y)), fmaxf(fabsf(v1.z), fabsf(v1.w))));
        m2 = fmaxf(m2, fmaxf(fmaxf(fabsf(v2.x), fabsf(v2.y)), fmaxf(fabsf(v2.z), fabsf(v2.w))));
        m3 = fmaxf(m3, fmaxf(fmaxf(fabsf(v3.x), fabsf(v3.y)), fmaxf(fabsf(v3.z), fabsf(v3.w))));
    }
    for (; i < n4; i += S) {
        float4 v = x4[i];
        m0 = fmaxf(m0, fmaxf(fmaxf(fabsf(v.x), fabsf(v.y)), fmaxf(fabsf(v.z), fabsf(v.w))));
    }
    float m = fmaxf(fmaxf(m0, m1), fmaxf(m2, m3));
    #pragma unroll
    for (int off = 32; off > 0; off >>= 1) m = fmaxf(m, __shfl_xor(m, off, 64));
    if ((threadIdx.x & 63) == 0) atomicMax(out, __float_as_uint(m));
}

// ---------------- scale finalize ----------------
__global__ void k_scale(const float* __restrict__ clip, const unsigned int* __restrict__ maxbits,
                        float* __restrict__ s_out) {
    float m = __uint_as_float(*maxbits);
    float sig = 1.f / (1.f + expf(-clip[0]));
    float s = sig * m / 127.f;
    s_out[0] = s;
    s_out[1] = 1.f / s;
}

// ---------------- quantize fp32 -> packed int8 ----------------
__global__ void k_quant_f32_i8(const float* __restrict__ in, int4* __restrict__ out,
                               const float* __restrict__ sptr, size_t n16) {
    float r = sptr[1];
    size_t S = (size_t)gridDim.x * blockDim.x;
    size_t i = (size_t)blockIdx.x * blockDim.x + threadIdx.x;
    const float4* in4 = (const float4*)in;
    for (; i < n16; i += S) {
        float4 v0 = in4[4 * i], v1 = in4[4 * i + 1], v2 = in4[4 * i + 2], v3 = in4[4 * i + 3];
        int4 o;
        o.x = pack4(v0, r); o.y = pack4(v1, r); o.z = pack4(v2, r); o.w = pack4(v3, r);
        out[i] = o;
    }
}

// ---------------- quantize h16 (per-block scale) -> packed int8 ----------------
__global__ void k_quant_h16_i8(const short* __restrict__ h16, const float* __restrict__ sblk,
                               const float* __restrict__ sh, int4* __restrict__ qh, size_t nchunks) {
    const float rh = sh[1] * (1.f / 32766.f);
    size_t S = (size_t)gridDim.x * blockDim.x;
    size_t i = (size_t)blockIdx.x * blockDim.x + threadIdx.x;
    for (; i < nchunks; i += S) {
        int row = (int)(i / 176);
        int col = (int)(i - (size_t)row * 176) * 16;
        float f = sblk[(row >> 8) * 22 + (col >> 7)] * rh;
        const int4* p = (const int4*)(h16 + (size_t)row * 2816 + col);
        int4 lo = p[0], hi = p[1];
        int w[8] = {lo.x, lo.y, lo.z, lo.w, hi.x, hi.y, hi.z, hi.w};
        int ob[4];
        #pragma unroll
        for (int j = 0; j < 4; ++j) {
            int q0 = q1mul((float)(short)(w[2 * j] & 0xFFFF), f);
            int q1 = q1mul((float)(short)(w[2 * j] >> 16), f);
            int q2 = q1mul((float)(short)(w[2 * j + 1] & 0xFFFF), f);
            int q3 = q1mul((float)(short)(w[2 * j + 1] >> 16), f);
            ob[j] = (q0 & 255) | ((q1 & 255) << 8) | ((q2 & 255) << 16) | ((q3 & 255) << 24);
        }
        int4 o; o.x = ob[0]; o.y = ob[1]; o.z = ob[2]; o.w = ob[3];
        qh[i] = o;
    }
}

// ---------------- per-row weight quantization ----------------
__global__ void k_quant_w_i8(const float* __restrict__ W, int8_t* __restrict__ Q,
                             float* __restrict__ srow, int cols) {
    int row = blockIdx.x;
    const float* w = W + (size_t)row * cols;
    float m = 0.f;
    for (int c = threadIdx.x; c < cols; c += 256) m = fmaxf(m, fabsf(w[c]));
    #pragma unroll
    for (int off = 32; off > 0; off >>= 1) m = fmaxf(m, __shfl_xor(m, off, 64));
    __shared__ float red[4];
    if ((threadIdx.x & 63) == 0) red[threadIdx.x >> 6] = m;
    __syncthreads();
    if (threadIdx.x == 0) {
        float mm = fmaxf(fmaxf(red[0], red[1]), fmaxf(red[2], red[3]));
        red[0] = mm / 127.f;
        srow[row] = mm / 127.f;
    }
    __syncthreads();
    float s = red[0];
    for (int c = threadIdx.x; c < cols; c += 256)
        Q[(size_t)row * cols + c] = (int8_t)q1div(w[c], s);
}

// 8 MFMA per phase: 4 m-blocks x (gate,up)
#define MFMA8_G1(AF, BG, BU)                                                                  \
    _Pragma("unroll")                                                                         \
    for (int m = 0; m < 4; ++m) {                                                             \
        accg[m] = __builtin_amdgcn_mfma_i32_32x32x32_i8(AF[m], BG, accg[m], 0, 0, 0);         \
        accu[m] = __builtin_amdgcn_mfma_i32_32x32x32_i8(AF[m], BU, accu[m], 0, 0, 0);         \
    }

// ================= GEMM1 (gate+up) — 32x32x32 MFMA, R9 read-ahead skeleton =================
// Tile 256x128(g,u), BK=128 = 4 ksteps of 32B. Wave tile 128x32 per matrix = 4 m-blocks of 32x32.
// LDS/buf 64K: A0@0 A1@16K G0@32K U0@40K G1@48K U1@56K (identical staging to R9).
// Per phase: consume kstep s, read-ahead kstep s+1 (4 A + 2 B ds_read_b128), 8 MFMA.
__global__ __launch_bounds__(512, 2) void k_gemm1_i8(
    const int8_t* __restrict__ Aq, const int8_t* __restrict__ Bg, const int8_t* __restrict__ Bu,
    const float* __restrict__ sg, const float* __restrict__ su, const float* __restrict__ sx,
    short* __restrict__ H16, float* __restrict__ sblk, unsigned int* __restrict__ maxh,
    int nt_base)
{
    constexpr int K = 1024, N = 2816, NT = K / 128, BUF = 65536;
    __shared__ int8_t lds[2 * BUF];

    const int wgl = (int)blockIdx.x >> 3;
    const int xcd = (int)blockIdx.x & 7;
    const int mtspan = (int)(gridDim.x >> 3) / 11;
    const int mt = xcd * mtspan + wgl / 11;
    const int nt = nt_base + wgl % 11;
    const int m0 = mt * 256, n0 = nt * 128;
    const int tid = threadIdx.x;
    const int wid = tid >> 6, lane = tid & 63;
    const int wm = wid >> 2, wn = wid & 3;
    const int l31 = lane & 31, l5 = lane >> 5;
    const int lp = (l31 >> 1) & 3;                    // stored-chunk XOR key (row>>1)&3

    // staging: linear LDS dest, inverse-swizzled global source (rule #21) — unchanged from R9
    const int srow = tid >> 2;
    const int scol = ((tid & 3) ^ ((srow >> 1) & 3)) << 4;
    const int8_t* gA0 = Aq + (size_t)(m0 + srow) * K + scol;
    const int8_t* gA1 = gA0 + (size_t)128 * K;
    const int8_t* gG  = Bg + (size_t)(n0 + srow) * K + scol;
    const int8_t* gU  = Bu + (size_t)(n0 + srow) * K + scol;
    const int ldst = wid << 10;

    // fragment offsets: kstep s -> slab (s>>1)*16384, chunk ((s&1)*2 + l5) ^ lp
    const int F0 = ((l5 ^ lp) << 4);
    const int F1 = (((2 + l5) ^ lp) << 4);
    const int F2 = 16384 + F0, F3 = 16384 + F1;
    int aR[4];
    #pragma unroll
    for (int m = 0; m < 4; ++m) aR[m] = (wm * 128 + m * 32 + l31) * 64;
    const int bRg = 32768 + (wn * 32 + l31) * 64;
    const int bRu = bRg + 8192;

    i32x16 accg[4] = {};
    i32x16 accu[4] = {};
    i32x4 aA[4], aB[4], bgA, buA, bgB, buB;

    // prologue: stage tile 0 (order A0,G0U0 | A1,G1U1)
    {
        int8_t* Lw = &lds[0];
        GLD16(gA0,      Lw + ldst);         GLD16(gA1,      Lw + 8192  + ldst);
        GLD16(gG,       Lw + 32768 + ldst); GLD16(gU,       Lw + 40960 + ldst);
        GLD16(gA0 + 64, Lw + 16384 + ldst); GLD16(gA1 + 64, Lw + 24576 + ldst);
        GLD16(gG  + 64, Lw + 49152 + ldst); GLD16(gU  + 64, Lw + 57344 + ldst);
    }
    GATE(4);                                          // slab0 of tile 0 landed
    {
        const int8_t* Lr = &lds[0];
        #pragma unroll
        for (int m = 0; m < 4; ++m) aA[m] = *(const i32x4*)(Lr + aR[m] + F0);
        bgA = *(const i32x4*)(Lr + bRg + F0);
        buA = *(const i32x4*)(Lr + bRu + F0);
    }

    for (int t = 0; t < NT; ++t) {
        const bool st = (t + 1 < NT);
        const int8_t* Lr = &lds[(t & 1) * BUF];
        int8_t* Lw = &lds[((t + 1) & 1) * BUF];
        const size_t kk = (size_t)(t + 1) * 128;

        // pA: consume ks0; read ks1; stage A-slab0(t+1)
        #pragma unroll
        for (int m = 0; m < 4; ++m) aB[m] = *(const i32x4*)(Lr + aR[m] + F1);
        bgB = *(const i32x4*)(Lr + bRg + F1);
        buB = *(const i32x4*)(Lr + bRu + F1);
        if (st) { GLD16(gA0 + kk, Lw + ldst); GLD16(gA1 + kk, Lw + 8192 + ldst); }
        SCHEDB();
        __builtin_amdgcn_s_setprio(1);
        MFMA8_G1(aA, bgA, buA);
        __builtin_amdgcn_s_setprio(0);
        // gate2: pB reads slab1(t) staged in pC(t-1); outstanding = pC(t-1)4 + pA2 -> vmcnt(2)
        if (st) { GATE(2); } else { GATE(0); }

        // pB: consume ks1; read ks2 (slab1); stage G0U0(t+1)
        #pragma unroll
        for (int m = 0; m < 4; ++m) aA[m] = *(const i32x4*)(Lr + aR[m] + F2);
        bgA = *(const i32x4*)(Lr + bRg + F2);
        buA = *(const i32x4*)(Lr + bRu + F2);
        if (st) { GLD16(gG + kk, Lw + 32768 + ldst); GLD16(gU + kk, Lw + 40960 + ldst); }
        SCHEDB();
        __builtin_amdgcn_s_setprio(1);
        MFMA8_G1(aB, bgB, buB);
        __builtin_amdgcn_s_setprio(0);

        // pC: consume ks2; read ks3; stage slab1(t+1) (4 loads)
        #pragma unroll
        for (int m = 0; m < 4; ++m) aB[m] = *(const i32x4*)(Lr + aR[m] + F3);
        bgB = *(const i32x4*)(Lr + bRg + F3);
        buB = *(const i32x4*)(Lr + bRu + F3);
        if (st) { GLD16(gA0 + kk + 64, Lw + 16384 + ldst); GLD16(gA1 + kk + 64, Lw + 24576 + ldst);
                  GLD16(gG + kk + 64, Lw + 49152 + ldst);  GLD16(gU + kk + 64, Lw + 57344 + ldst); }
        SCHEDB();
        __builtin_amdgcn_s_setprio(1);
        MFMA8_G1(aA, bgA, buA);
        __builtin_amdgcn_s_setprio(0);
        // gate1: pD reads slab0(t+1) staged in pA/pB(t); outstanding = pA2+pB2+pC4 -> vmcnt(4)
        if (st) { GATE(4); } else { GATE(0); }

        // pD: consume ks3; read (t+1) ks0 from Lw
        if (st) {
            #pragma unroll
            for (int m = 0; m < 4; ++m) aA[m] = *(const i32x4*)(Lw + aR[m] + F0);
            bgA = *(const i32x4*)(Lw + bRg + F0);
            buA = *(const i32x4*)(Lw + bRu + F0);
        }
        SCHEDB();
        __builtin_amdgcn_s_setprio(1);
        MFMA8_G1(aB, bgB, buB);
        __builtin_amdgcn_s_setprio(0);
    }
    BARRIER();                                        // frag reads drained before h overwrites LDS

    // ---- epilogue: single SwiGLU pass -> f32 LDS tile -> coalesced int16 stores ----
    // C/D: col = lane&31 (fixed per thread), row = (r&3)+8*(r>>2)+4*l5 within 32x32 block
    const float s_x = sx[0];
    const int col = wn * 32 + l31;
    const float fg = s_x * sg[n0 + col];
    const float fu = s_x * su[n0 + col];
    float lmax = 0.f;
    #pragma unroll
    for (int m = 0; m < 4; ++m) {
        #pragma unroll
        for (int r = 0; r < 16; ++r) {
            const int row = wm * 128 + m * 32 + (r & 3) + 8 * (r >> 2) + 4 * l5;
            float g = (float)accg[m][r] * fg;
            float u = (float)accu[m][r] * fu;
            float h = g * u / (1.f + expf(-g));
            *(float*)(lds + (row << 9) + (col << 2)) = h;
            lmax = fmaxf(lmax, fabsf(h));
        }
    }
    #pragma unroll
    for (int off = 32; off > 0; off >>= 1) lmax = fmaxf(lmax, __shfl_xor(lmax, off, 64));
    unsigned int* slot = (unsigned int*)&sblk[mt * 22 + nt];
    if (lane == 0) atomicMax(slot, __float_as_uint(lmax));
    BARRIER();
    const float bmax = __uint_as_float(*slot);
    if (tid == 0) atomicMax(maxh, __float_as_uint(bmax));
    const float qs = 32766.f / fmaxf(bmax, 1e-20f);
    uint* H16u = (uint*)H16;
    #pragma unroll
    for (int k = 0; k < 32; ++k) {
        const int fidx = 2 * (tid + k * 512);
        const int row = fidx >> 7, c2 = fidx & 127;
        const float2 hv = *(const float2*)(lds + (fidx << 2));
        const int s0 = (int)rintf(hv.x * qs), s1 = (int)rintf(hv.y * qs);
        H16u[((size_t)(m0 + row) * N + n0 + c2) >> 1] = (s0 & 0xFFFF) | (s1 << 16);
    }
}

#define MFMA8_G2(AF, BF0, BF1)                                                                \
    _Pragma("unroll")                                                                         \
    for (int m = 0; m < 4; ++m) {                                                             \
        acc0[m] = __builtin_amdgcn_mfma_i32_32x32x32_i8(AF[m], BF0, acc0[m], 0, 0, 0);        \
        acc1[m] = __builtin_amdgcn_mfma_i32_32x32x32_i8(AF[m], BF1, acc1[m], 0, 0, 0);        \
    }

// ================= GEMM2 — 32x32x32 MFMA, same skeleton, 256x256 =================
// Wave tile 128x64 = 4 m-blocks x 2 n-blocks. LDS/buf: A0@0 A1@16K B0@32K B1@48K.
__global__ __launch_bounds__(512, 2) void k_gemm2_i8(
    const int8_t* __restrict__ Aq, const int8_t* __restrict__ Bw,
    const float* __restrict__ sw, const float* __restrict__ sh,
    float* __restrict__ Out)
{
    constexpr int K = 2816, N = 1024, NT = K / 128, BUF = 65536;   // NT = 22
    __shared__ int8_t lds[2 * BUF];

    const int chunk = gridDim.x >> 3;                // grid = 1024 = 8*128
    const int wg = ((int)blockIdx.x & 7) * chunk + ((int)blockIdx.x >> 3);
    const int mt = wg >> 2, nt = wg & 3;
    const int m0 = mt * 256, n0 = nt * 256;
    const int tid = threadIdx.x;
    const int wid = tid >> 6, lane = tid & 63;
    const int wm = wid >> 2, wn = wid & 3;
    const int l31 = lane & 31, l5 = lane >> 5;
    const int lp = (l31 >> 1) & 3;

    const int srow = tid >> 2;
    const int scol = ((tid & 3) ^ ((srow >> 1) & 3)) << 4;
    const int8_t* gA0 = Aq + (size_t)(m0 + srow) * K + scol;
    const int8_t* gA1 = gA0 + (size_t)128 * K;
    const int8_t* gB0 = Bw + (size_t)(n0 + srow) * K + scol;
    const int8_t* gB1 = gB0 + (size_t)128 * K;
    const int ldst = wid << 10;

    const int F0 = ((l5 ^ lp) << 4);
    const int F1 = (((2 + l5) ^ lp) << 4);
    const int F2 = 16384 + F0, F3 = 16384 + F1;
    int aR[4];
    #pragma unroll
    for (int m = 0; m < 4; ++m) aR[m] = (wm * 128 + m * 32 + l31) * 64;
    const int bR0 = 32768 + (wn * 64 + l31) * 64;
    const int bR1 = bR0 + 2048;                      // +32 rows

    i32x16 acc0[4] = {};
    i32x16 acc1[4] = {};
    i32x4 aA[4], aB[4], b0A, b1A, b0B, b1B;

    {
        int8_t* Lw = &lds[0];
        GLD16(gA0,      Lw + ldst);         GLD16(gA1,      Lw + 8192  + ldst);
        GLD16(gB0,      Lw + 32768 + ldst); GLD16(gB1,      Lw + 40960 + ldst);
        GLD16(gA0 + 64, Lw + 16384 + ldst); GLD16(gA1 + 64, Lw + 24576 + ldst);
        GLD16(gB0 + 64, Lw + 49152 + ldst); GLD16(gB1 + 64, Lw + 57344 + ldst);
    }
    GATE(4);
    {
        const int8_t* Lr = &lds[0];
        #pragma unroll
        for (int m = 0; m < 4; ++m) aA[m] = *(const i32x4*)(Lr + aR[m] + F0);
        b0A = *(const i32x4*)(Lr + bR0 + F0);
        b1A = *(const i32x4*)(Lr + bR1 + F0);
    }

    for (int t = 0; t < NT; ++t) {
        const bool st = (t + 1 < NT);
        const int8_t* Lr = &lds[(t & 1) * BUF];
        int8_t* Lw = &lds[((t + 1) & 1) * BUF];
        const size_t kk = (size_t)(t + 1) * 128;

        // pA
        #pragma unroll
        for (int m = 0; m < 4; ++m) aB[m] = *(const i32x4*)(Lr + aR[m] + F1);
        b0B = *(const i32x4*)(Lr + bR0 + F1);
        b1B = *(const i32x4*)(Lr + bR1 + F1);
        if (st) { GLD16(gA0 + kk, Lw + ldst); GLD16(gA1 + kk, Lw + 8192 + ldst); }
        SCHEDB();
        __builtin_amdgcn_s_setprio(1);
        MFMA8_G2(aA, b0A, b1A);
        __builtin_amdgcn_s_setprio(0);
        if (st) { GATE(2); } else { GATE(0); }

        // pB
        #pragma unroll
        for (int m = 0; m < 4; ++m) aA[m] = *(const i32x4*)(Lr + aR[m] + F2);
        b0A = *(const i32x4*)(Lr + bR0 + F2);
        b1A = *(const i32x4*)(Lr + bR1 + F2);
        if (st) { GLD16(gB0 + kk, Lw + 32768 + ldst); GLD16(gB1 + kk, Lw + 40960 + ldst); }
        SCHEDB();
        __builtin_amdgcn_s_setprio(1);
        MFMA8_G2(aB, b0B, b1B);
        __builtin_amdgcn_s_setprio(0);

        // pC
        #pragma unroll
        for (int m = 0; m < 4; ++m) aB[m] = *(const i32x4*)(Lr + aR[m] + F3);
        b0B = *(const i32x4*)(Lr + bR0 + F3);
        b1B = *(const i32x4*)(Lr + bR1 + F3);
        if (st) { GLD16(gA0 + kk + 64, Lw + 16384 + ldst); GLD16(gA1 + kk + 64, Lw + 24576 + ldst);
                  GLD16(gB0 + kk + 64, Lw + 49152 + ldst); GLD16(gB1 + kk + 64, Lw + 57344 + ldst); }
        SCHEDB();
        __builtin_amdgcn_s_setprio(1);
        MFMA8_G2(aA, b0A, b1A);
        __builtin_amdgcn_s_setprio(0);
        if (st) { GATE(4); } else { GATE(0); }

        // pD
        if (st) {
            #pragma unroll
            for (int m = 0; m < 4; ++m) aA[m] = *(const i32x4*)(Lw + aR[m] + F0);
            b0A = *(const i32x4*)(Lw + bR0 + F0);
            b1A = *(const i32x4*)(Lw + bR1 + F0);
        }
        SCHEDB();
        __builtin_amdgcn_s_setprio(1);
        MFMA8_G2(aB, b0B, b1B);
        __builtin_amdgcn_s_setprio(0);
    }

    const float s_h = sh[0];
    #pragma unroll
    for (int nb = 0; nb < 2; ++nb) {
        const int n = n0 + wn * 64 + nb * 32 + l31;
        const float f = s_h * sw[n];
        #pragma unroll
        for (int m = 0; m < 4; ++m) {
            #pragma unroll
            for (int r = 0; r < 16; ++r) {
                const int row = m0 + wm * 128 + m * 32 + (r & 3) + 8 * (r >> 2) + 4 * l5;
                const int v = nb ? acc1[m][r] : acc0[m][r];
                Out[(size_t)row * N + n] = (float)v * f;
            }
        }
    }
}

extern "C" void kernel_launch(void* const* d_in, const int* in_sizes, int n_in,
                              void* d_out, int out_size, void* d_ws, size_t ws_size,
                              hipStream_t stream) {
    const float* x       = (const float*)d_in[0];
    const float* clip_x  = (const float*)d_in[1];
    const float* clip_dn = (const float*)d_in[2];
    const float* w_gate  = (const float*)d_in[3];
    const float* w_up    = (const float*)d_in[4];
    const float* w_down  = (const float*)d_in[5];
    float* out = (float*)d_out;

    const int Hd = 1024, Id = 2816;
    const int M = in_sizes[0] / Hd;                  // 65536
    const size_t nx = (size_t)M * Hd;
    const size_t nh = (size_t)M * Id;

    char* ws = (char*)d_ws;
    size_t off = 0;
    auto alloc = [&](size_t bytes) -> char* {
        char* p = ws + off;
        off = (off + bytes + 255) & ~(size_t)255;
        return p;
    };
    unsigned int* max_slots = (unsigned int*)alloc(8);   // [0]=max|x|, [1]=max|h|
    float* sxp = (float*)alloc(8);
    float* shp = (float*)alloc(8);
    int8_t* qx  = (int8_t*)alloc(nx);
    int8_t* qwg = (int8_t*)alloc((size_t)Id * Hd);
    int8_t* qwu = (int8_t*)alloc((size_t)Id * Hd);
    int8_t* qwd = (int8_t*)alloc((size_t)Hd * Id);
    float* swg = (float*)alloc((size_t)Id * 4);
    float* swu = (float*)alloc((size_t)Id * 4);
    float* swd = (float*)alloc((size_t)Hd * 4);
    int8_t* qh = (int8_t*)alloc(nh);
    short* h16 = (short*)alloc(nh * 2);
    const size_t sblk_bytes = (size_t)(M / 256) * 22 * 4;
    float* sblk = (float*)alloc(sblk_bytes);

    hipMemsetAsync(max_slots, 0, 8, stream);
    hipMemsetAsync(sblk, 0, sblk_bytes, stream);

    k_absmax<<<4096, 256, 0, stream>>>(x, nx / 4, &max_slots[0]);
    k_scale<<<1, 1, 0, stream>>>(clip_x, &max_slots[0], sxp);
    k_quant_f32_i8<<<2048, 256, 0, stream>>>(x, (int4*)qx, sxp, nx / 16);
    k_quant_w_i8<<<Id, 256, 0, stream>>>(w_gate, qwg, swg, Hd);
    k_quant_w_i8<<<Id, 256, 0, stream>>>(w_up, qwu, swu, Hd);
    k_quant_w_i8<<<Hd, 256, 0, stream>>>(w_down, qwd, swd, Id);

    const int g1grid = (M / 256) * 11;               // per nt-half
    k_gemm1_i8<<<g1grid, 512, 0, stream>>>(qx, qwg, qwu, swg, swu, sxp, h16, sblk, &max_slots[1], 0);
    k_gemm1_i8<<<g1grid, 512, 0, stream>>>(qx, qwg, qwu, swg, swu, sxp, h16, sblk, &max_slots[1], 11);
    k_scale<<<1, 1, 0, stream>>>(clip_dn, &max_slots[1], shp);
    k_quant_h16_i8<<<4096, 256, 0, stream>>>(h16, sblk, shp, (int4*)qh, nh / 16);

    k_gemm2_i8<<<(M / 256) * (Hd / 256), 512, 0, stream>>>(qh, qwd, swd, shp, out);
}

// Round 11
// 1151.196 us; speedup vs baseline: 1.0150x; 1.0150x over previous
//
#include <hip/hip_runtime.h>
#include <stdint.h>

typedef __attribute__((ext_vector_type(4))) int i32x4;

typedef const __attribute__((address_space(1))) void gvoid_t;
typedef __attribute__((address_space(3))) void lvoid_t;

#define GLD16(g, l) __builtin_amdgcn_global_load_lds((gvoid_t*)(g), (lvoid_t*)(l), 16, 0, 0)
#define FENCE() asm volatile("" ::: "memory")
#define BARRIER() do { FENCE(); __builtin_amdgcn_s_barrier(); FENCE(); } while (0)
#define GATE4() asm volatile("s_waitcnt vmcnt(4)\n\ts_barrier" ::: "memory")
#define GATE0() asm volatile("s_waitcnt vmcnt(0)\n\ts_barrier" ::: "memory")

__device__ inline int q1mul(float x, float r) {
    return (int)fminf(fmaxf(rintf(x * r), -128.f), 127.f);
}
__device__ inline int q1div(float x, float s) {
    return (int)fminf(fmaxf(rintf(x / s), -128.f), 127.f);
}
__device__ inline int pack4(float4 v, float r) {
    return (q1mul(v.x, r) & 255) | ((q1mul(v.y, r) & 255) << 8) |
           ((q1mul(v.z, r) & 255) << 16) | ((q1mul(v.w, r) & 255) << 24);
}

// ---------------- global absmax (4 independent chains) ----------------
__global__ void k_absmax(const float* __restrict__ x, size_t n4, unsigned int* __restrict__ out) {
    size_t S = (size_t)gridDim.x * blockDim.x;
    size_t i = (size_t)blockIdx.x * blockDim.x + threadIdx.x;
    const float4* x4 = (const float4*)x;
    float m0 = 0.f, m1 = 0.f, m2 = 0.f, m3 = 0.f;
    for (; i + 3 * S < n4; i += 4 * S) {
        float4 v0 = x4[i], v1 = x4[i + S], v2 = x4[i + 2 * S], v3 = x4[i + 3 * S];
        m0 = fmaxf(m0, fmaxf(fmaxf(fabsf(v0.x), fabsf(v0.y)), fmaxf(fabsf(v0.z), fabsf(v0.w))));
        m1 = fmaxf(m1, fmaxf(fmaxf(fabsf(v1.x), fabsf(v1.y)), fmaxf(fabsf(v1.z), fabsf(v1.w))));
        m2 = fmaxf(m2, fmaxf(fmaxf(fabsf(v2.x), fabsf(v2.y)), fmaxf(fabsf(v2.z), fabsf(v2.w))));
        m3 = fmaxf(m3, fmaxf(fmaxf(fabsf(v3.x), fabsf(v3.y)), fmaxf(fabsf(v3.z), fabsf(v3.w))));
    }
    for (; i < n4; i += S) {
        float4 v = x4[i];
        m0 = fmaxf(m0, fmaxf(fmaxf(fabsf(v.x), fabsf(v.y)), fmaxf(fabsf(v.z), fabsf(v.w))));
    }
    float m = fmaxf(fmaxf(m0, m1), fmaxf(m2, m3));
    #pragma unroll
    for (int off = 32; off > 0; off >>= 1) m = fmaxf(m, __shfl_xor(m, off, 64));
    if ((threadIdx.x & 63) == 0) atomicMax(out, __float_as_uint(m));
}

// ---------------- scale finalize ----------------
__global__ void k_scale(const float* __restrict__ clip, const unsigned int* __restrict__ maxbits,
                        float* __restrict__ s_out) {
    float m = __uint_as_float(*maxbits);
    float sig = 1.f / (1.f + expf(-clip[0]));
    float s = sig * m / 127.f;
    s_out[0] = s;
    s_out[1] = 1.f / s;
}

// ---------------- quantize fp32 -> packed int8 ----------------
__global__ void k_quant_f32_i8(const float* __restrict__ in, int4* __restrict__ out,
                               const float* __restrict__ sptr, size_t n16) {
    float r = sptr[1];
    size_t S = (size_t)gridDim.x * blockDim.x;
    size_t i = (size_t)blockIdx.x * blockDim.x + threadIdx.x;
    const float4* in4 = (const float4*)in;
    for (; i < n16; i += S) {
        float4 v0 = in4[4 * i], v1 = in4[4 * i + 1], v2 = in4[4 * i + 2], v3 = in4[4 * i + 3];
        int4 o;
        o.x = pack4(v0, r); o.y = pack4(v1, r); o.z = pack4(v2, r); o.w = pack4(v3, r);
        out[i] = o;
    }
}

// ---------------- quantize h16 (per-block scale) -> packed int8 ----------------
__global__ void k_quant_h16_i8(const short* __restrict__ h16, const float* __restrict__ sblk,
                               const float* __restrict__ sh, int4* __restrict__ qh, size_t nchunks) {
    const float rh = sh[1] * (1.f / 32766.f);
    size_t S = (size_t)gridDim.x * blockDim.x;
    size_t i = (size_t)blockIdx.x * blockDim.x + threadIdx.x;
    for (; i < nchunks; i += S) {
        int row = (int)(i / 176);
        int col = (int)(i - (size_t)row * 176) * 16;
        float f = sblk[(row >> 8) * 22 + (col >> 7)] * rh;
        const int4* p = (const int4*)(h16 + (size_t)row * 2816 + col);
        int4 lo = p[0], hi = p[1];
        int w[8] = {lo.x, lo.y, lo.z, lo.w, hi.x, hi.y, hi.z, hi.w};
        int ob[4];
        #pragma unroll
        for (int j = 0; j < 4; ++j) {
            int q0 = q1mul((float)(short)(w[2 * j] & 0xFFFF), f);
            int q1 = q1mul((float)(short)(w[2 * j] >> 16), f);
            int q2 = q1mul((float)(short)(w[2 * j + 1] & 0xFFFF), f);
            int q3 = q1mul((float)(short)(w[2 * j + 1] >> 16), f);
            ob[j] = (q0 & 255) | ((q1 & 255) << 8) | ((q2 & 255) << 16) | ((q3 & 255) << 24);
        }
        int4 o; o.x = ob[0]; o.y = ob[1]; o.z = ob[2]; o.w = ob[3];
        qh[i] = o;
    }
}

// ---------------- per-row weight quantization ----------------
__global__ void k_quant_w_i8(const float* __restrict__ W, int8_t* __restrict__ Q,
                             float* __restrict__ srow, int cols) {
    int row = blockIdx.x;
    const float* w = W + (size_t)row * cols;
    float m = 0.f;
    for (int c = threadIdx.x; c < cols; c += 256) m = fmaxf(m, fabsf(w[c]));
    #pragma unroll
    for (int off = 32; off > 0; off >>= 1) m = fmaxf(m, __shfl_xor(m, off, 64));
    __shared__ float red[4];
    if ((threadIdx.x & 63) == 0) red[threadIdx.x >> 6] = m;
    __syncthreads();
    if (threadIdx.x == 0) {
        float mm = fmaxf(fmaxf(red[0], red[1]), fmaxf(red[2], red[3]));
        red[0] = mm / 127.f;
        srow[row] = mm / 127.f;
    }
    __syncthreads();
    float s = red[0];
    for (int c = threadIdx.x; c < cols; c += 256)
        Q[(size_t)row * cols + c] = (int8_t)q1div(w[c], s);
}

// ================= GEMM1 (gate+up) — m201-rhythm: BK=64, 3-buf ring, 4 phases/tile =================
// Tile 256x128(g,u each), 512 thr (8 waves 2Mx4N), wave 128x32 per matrix.
// Ring: 3 bufs x 32 KB (A[256][64]@0 | G[128][64]@16K | U[128][64]@24K). lds=128K for epilogue reuse.
// Tile t: 4 phases q: {read A-frags 2q,2q+1 (+B frags at q0); stage q-th load of tile t+2;
//   BARRIER; setprio 8 MFMA setprio; BARRIER}. Gate once per tile: outstanding = (t+1)'s 4 +
//   (t+2)'s 4 if staged -> vmcnt(4) proves t+1 landed; tails use vmcnt(0).
__global__ __launch_bounds__(512, 2) void k_gemm1_i8(
    const int8_t* __restrict__ Aq, const int8_t* __restrict__ Bg, const int8_t* __restrict__ Bu,
    const float* __restrict__ sg, const float* __restrict__ su, const float* __restrict__ sx,
    short* __restrict__ H16, float* __restrict__ sblk, unsigned int* __restrict__ maxh,
    int nt_base)
{
    constexpr int K = 1024, N = 2816, NT = K / 64, TB = 32768;   // NT = 16
    __shared__ int8_t lds[131072];   // ring uses first 96 KB; epilogue uses all 128 KB

    const int wgl = (int)blockIdx.x >> 3;
    const int xcd = (int)blockIdx.x & 7;
    const int mtspan = (int)(gridDim.x >> 3) / 11;
    const int mt = xcd * mtspan + wgl / 11;
    const int nt = nt_base + wgl % 11;
    const int m0 = mt * 256, n0 = nt * 128;
    const int tid = threadIdx.x;
    const int wid = tid >> 6, lane = tid & 63;
    const int wm = wid >> 2, wn = wid & 3;
    const int lr = lane & 15, lk = lane >> 4;

    // staging: linear LDS dest, inverse-swizzled global source (rule #21)
    const int srow = tid >> 2;
    const int scol = ((tid & 3) ^ ((srow >> 1) & 3)) << 4;
    const int8_t* gA0 = Aq + (size_t)(m0 + srow) * K + scol;
    const int8_t* gA1 = gA0 + (size_t)128 * K;
    const int8_t* gG  = Bg + (size_t)(n0 + srow) * K + scol;
    const int8_t* gU  = Bu + (size_t)(n0 + srow) * K + scol;
    const int ldst = wid << 10;

    const int swz = (lk ^ ((lr >> 1) & 3)) << 4;
    int offA[8], offG[2], offU[2];
    #pragma unroll
    for (int mi = 0; mi < 8; ++mi) offA[mi] = (wm * 128 + mi * 16 + lr) * 64 + swz;
    #pragma unroll
    for (int ni = 0; ni < 2; ++ni) {
        offG[ni] = 16384 + (wn * 32 + ni * 16 + lr) * 64 + swz;
        offU[ni] = 24576 + (wn * 32 + ni * 16 + lr) * 64 + swz;
    }

    i32x4 accg[8][2] = {};
    i32x4 accu[8][2] = {};

    auto stage1 = [&](int t, int q) {                // q-th wave-load of tile t into buf t%3
        int8_t* L = &lds[(t % 3) * TB];
        const size_t k0 = (size_t)t * 64;
        if (q == 0)      GLD16(gA0 + k0, L + ldst);
        else if (q == 1) GLD16(gA1 + k0, L + 8192  + ldst);
        else if (q == 2) GLD16(gG  + k0, L + 16384 + ldst);
        else             GLD16(gU  + k0, L + 24576 + ldst);
    };

    // prologue: stage tiles 0 and 1; tile0 landed (vmcnt(4)), tile1 in flight
    #pragma unroll
    for (int q = 0; q < 4; ++q) stage1(0, q);
    #pragma unroll
    for (int q = 0; q < 4; ++q) stage1(1, q);
    GATE4();

    for (int t = 0; t < NT; ++t) {
        const int8_t* L = &lds[(t % 3) * TB];
        const bool st2 = (t + 2 < NT);
        i32x4 bg[2], bu[2];
        #pragma unroll
        for (int q = 0; q < 4; ++q) {
            // reads for THIS phase (latency hidden by barrier: all waves wait together)
            i32x4 a0 = *(const i32x4*)(L + offA[2 * q]);
            i32x4 a1 = *(const i32x4*)(L + offA[2 * q + 1]);
            if (q == 0) {
                #pragma unroll
                for (int ni = 0; ni < 2; ++ni) {
                    bg[ni] = *(const i32x4*)(L + offG[ni]);
                    bu[ni] = *(const i32x4*)(L + offU[ni]);
                }
            }
            if (st2) stage1(t + 2, q);
            BARRIER();
            __builtin_amdgcn_s_setprio(1);
            #pragma unroll
            for (int ni = 0; ni < 2; ++ni) {
                accg[2 * q][ni]     = __builtin_amdgcn_mfma_i32_16x16x64_i8(a0, bg[ni], accg[2 * q][ni], 0, 0, 0);
                accu[2 * q][ni]     = __builtin_amdgcn_mfma_i32_16x16x64_i8(a0, bu[ni], accu[2 * q][ni], 0, 0, 0);
                accg[2 * q + 1][ni] = __builtin_amdgcn_mfma_i32_16x16x64_i8(a1, bg[ni], accg[2 * q + 1][ni], 0, 0, 0);
                accu[2 * q + 1][ni] = __builtin_amdgcn_mfma_i32_16x16x64_i8(a1, bu[ni], accu[2 * q + 1][ni], 0, 0, 0);
            }
            __builtin_amdgcn_s_setprio(0);
            if (q == 3) { if (st2) { GATE4(); } else { GATE0(); } }
            else        { BARRIER(); }
        }
    }

    // ---- epilogue (R8-verified): single SwiGLU pass -> f32 LDS tile -> coalesced int16 stores ----
    const float s_x = sx[0];
    float lmax = 0.f;
    #pragma unroll
    for (int ni = 0; ni < 2; ++ni) {
        const int nl = wn * 32 + ni * 16 + lr;
        const float fg = s_x * sg[n0 + nl];
        const float fu = s_x * su[n0 + nl];
        #pragma unroll
        for (int mi = 0; mi < 8; ++mi) {
            const int rowb = wm * 128 + mi * 16 + lk * 4;
            #pragma unroll
            for (int r = 0; r < 4; ++r) {
                float g = (float)accg[mi][ni][r] * fg;
                float u = (float)accu[mi][ni][r] * fu;
                float h = g * u / (1.f + expf(-g));
                *(float*)(lds + ((rowb + r) << 9) + (nl << 2)) = h;
                lmax = fmaxf(lmax, fabsf(h));
            }
        }
    }
    #pragma unroll
    for (int off = 32; off > 0; off >>= 1) lmax = fmaxf(lmax, __shfl_xor(lmax, off, 64));
    unsigned int* slot = (unsigned int*)&sblk[mt * 22 + nt];
    if (lane == 0) atomicMax(slot, __float_as_uint(lmax));
    BARRIER();
    const float bmax = __uint_as_float(*slot);
    if (tid == 0) atomicMax(maxh, __float_as_uint(bmax));
    const float qs = 32766.f / fmaxf(bmax, 1e-20f);
    uint* H16u = (uint*)H16;
    #pragma unroll
    for (int k = 0; k < 32; ++k) {
        const int fidx = 2 * (tid + k * 512);
        const int row = fidx >> 7, c2 = fidx & 127;
        const float2 hv = *(const float2*)(lds + (fidx << 2));
        const int s0 = (int)rintf(hv.x * qs), s1 = (int)rintf(hv.y * qs);
        H16u[((size_t)(m0 + row) * N + n0 + c2) >> 1] = (s0 & 0xFFFF) | (s1 << 16);
    }
}

// ================= GEMM2 — same rhythm, 256x256, NT=44 =================
// Ring buf 32 KB: A[256][64]@0 (A0 rows0-127 @0, A1 @8K) | B[256][64]@16K (B0 @16K, B1 @24K).
__global__ __launch_bounds__(512, 2) void k_gemm2_i8(
    const int8_t* __restrict__ Aq, const int8_t* __restrict__ Bw,
    const float* __restrict__ sw, const float* __restrict__ sh,
    float* __restrict__ Out)
{
    constexpr int K = 2816, N = 1024, NT = K / 64, TB = 32768;   // NT = 44
    __shared__ int8_t lds[3 * TB];

    const int chunk = gridDim.x >> 3;                // grid = 1024 = 8*128
    const int wg = ((int)blockIdx.x & 7) * chunk + ((int)blockIdx.x >> 3);
    const int mt = wg >> 2, nt = wg & 3;
    const int m0 = mt * 256, n0 = nt * 256;
    const int tid = threadIdx.x;
    const int wid = tid >> 6, lane = tid & 63;
    const int wm = wid >> 2, wn = wid & 3;
    const int lr = lane & 15, lk = lane >> 4;

    const int srow = tid >> 2;
    const int scol = ((tid & 3) ^ ((srow >> 1) & 3)) << 4;
    const int8_t* gA0 = Aq + (size_t)(m0 + srow) * K + scol;
    const int8_t* gA1 = gA0 + (size_t)128 * K;
    const int8_t* gB0 = Bw + (size_t)(n0 + srow) * K + scol;
    const int8_t* gB1 = gB0 + (size_t)128 * K;
    const int ldst = wid << 10;

    const int swz = (lk ^ ((lr >> 1) & 3)) << 4;
    int offA[8], offB[4];
    #pragma unroll
    for (int mi = 0; mi < 8; ++mi) offA[mi] = (wm * 128 + mi * 16 + lr) * 64 + swz;
    #pragma unroll
    for (int ni = 0; ni < 4; ++ni) offB[ni] = 16384 + (wn * 64 + ni * 16 + lr) * 64 + swz;

    i32x4 acc[8][4] = {};

    auto stage1 = [&](int t, int q) {
        int8_t* L = &lds[(t % 3) * TB];
        const size_t k0 = (size_t)t * 64;
        if (q == 0)      GLD16(gA0 + k0, L + ldst);
        else if (q == 1) GLD16(gA1 + k0, L + 8192  + ldst);
        else if (q == 2) GLD16(gB0 + k0, L + 16384 + ldst);
        else             GLD16(gB1 + k0, L + 24576 + ldst);
    };

    #pragma unroll
    for (int q = 0; q < 4; ++q) stage1(0, q);
    #pragma unroll
    for (int q = 0; q < 4; ++q) stage1(1, q);
    GATE4();

    for (int t = 0; t < NT; ++t) {
        const int8_t* L = &lds[(t % 3) * TB];
        const bool st2 = (t + 2 < NT);
        i32x4 b[4];
        #pragma unroll
        for (int q = 0; q < 4; ++q) {
            i32x4 a0 = *(const i32x4*)(L + offA[2 * q]);
            i32x4 a1 = *(const i32x4*)(L + offA[2 * q + 1]);
            if (q == 0) {
                #pragma unroll
                for (int ni = 0; ni < 4; ++ni) b[ni] = *(const i32x4*)(L + offB[ni]);
            }
            if (st2) stage1(t + 2, q);
            BARRIER();
            __builtin_amdgcn_s_setprio(1);
            #pragma unroll
            for (int ni = 0; ni < 4; ++ni) {
                acc[2 * q][ni]     = __builtin_amdgcn_mfma_i32_16x16x64_i8(a0, b[ni], acc[2 * q][ni], 0, 0, 0);
                acc[2 * q + 1][ni] = __builtin_amdgcn_mfma_i32_16x16x64_i8(a1, b[ni], acc[2 * q + 1][ni], 0, 0, 0);
            }
            __builtin_amdgcn_s_setprio(0);
            if (q == 3) { if (st2) { GATE4(); } else { GATE0(); } }
            else        { BARRIER(); }
        }
    }

    const float s_h = sh[0];
    #pragma unroll
    for (int ni = 0; ni < 4; ++ni) {
        const int n = n0 + wn * 64 + ni * 16 + lr;
        const float f = s_h * sw[n];
        #pragma unroll
        for (int mi = 0; mi < 8; ++mi) {
            const int mb = m0 + wm * 128 + mi * 16 + lk * 4;
            #pragma unroll
            for (int r = 0; r < 4; ++r)
                Out[(size_t)(mb + r) * N + n] = (float)acc[mi][ni][r] * f;
        }
    }
}

extern "C" void kernel_launch(void* const* d_in, const int* in_sizes, int n_in,
                              void* d_out, int out_size, void* d_ws, size_t ws_size,
                              hipStream_t stream) {
    const float* x       = (const float*)d_in[0];
    const float* clip_x  = (const float*)d_in[1];
    const float* clip_dn = (const float*)d_in[2];
    const float* w_gate  = (const float*)d_in[3];
    const float* w_up    = (const float*)d_in[4];
    const float* w_down  = (const float*)d_in[5];
    float* out = (float*)d_out;

    const int Hd = 1024, Id = 2816;
    const int M = in_sizes[0] / Hd;                  // 65536
    const size_t nx = (size_t)M * Hd;
    const size_t nh = (size_t)M * Id;

    char* ws = (char*)d_ws;
    size_t off = 0;
    auto alloc = [&](size_t bytes) -> char* {
        char* p = ws + off;
        off = (off + bytes + 255) & ~(size_t)255;
        return p;
    };
    unsigned int* max_slots = (unsigned int*)alloc(8);   // [0]=max|x|, [1]=max|h|
    float* sxp = (float*)alloc(8);
    float* shp = (float*)alloc(8);
    int8_t* qx  = (int8_t*)alloc(nx);
    int8_t* qwg = (int8_t*)alloc((size_t)Id * Hd);
    int8_t* qwu = (int8_t*)alloc((size_t)Id * Hd);
    int8_t* qwd = (int8_t*)alloc((size_t)Hd * Id);
    float* swg = (float*)alloc((size_t)Id * 4);
    float* swu = (float*)alloc((size_t)Id * 4);
    float* swd = (float*)alloc((size_t)Hd * 4);
    int8_t* qh = (int8_t*)alloc(nh);
    short* h16 = (short*)alloc(nh * 2);
    const size_t sblk_bytes = (size_t)(M / 256) * 22 * 4;
    float* sblk = (float*)alloc(sblk_bytes);

    hipMemsetAsync(max_slots, 0, 8, stream);
    hipMemsetAsync(sblk, 0, sblk_bytes, stream);

    k_absmax<<<4096, 256, 0, stream>>>(x, nx / 4, &max_slots[0]);
    k_scale<<<1, 1, 0, stream>>>(clip_x, &max_slots[0], sxp);
    k_quant_f32_i8<<<2048, 256, 0, stream>>>(x, (int4*)qx, sxp, nx / 16);
    k_quant_w_i8<<<Id, 256, 0, stream>>>(w_gate, qwg, swg, Hd);
    k_quant_w_i8<<<Id, 256, 0, stream>>>(w_up, qwu, swu, Hd);
    k_quant_w_i8<<<Hd, 256, 0, stream>>>(w_down, qwd, swd, Id);

    const int g1grid = (M / 256) * 11;               // per nt-half
    k_gemm1_i8<<<g1grid, 512, 0, stream>>>(qx, qwg, qwu, swg, swu, sxp, h16, sblk, &max_slots[1], 0);
    k_gemm1_i8<<<g1grid, 512, 0, stream>>>(qx, qwg, qwu, swg, swu, sxp, h16, sblk, &max_slots[1], 11);
    k_scale<<<1, 1, 0, stream>>>(clip_dn, &max_slots[1], shp);
    k_quant_h16_i8<<<4096, 256, 0, stream>>>(h16, sblk, shp, (int4*)qh, nh / 16);

    k_gemm2_i8<<<(M / 256) * (Hd / 256), 512, 0, stream>>>(qh, qwd, swd, shp, out);
}